// Round 14
// baseline (267.875 us; speedup 1.0000x reference)
//
#include <hip/hip_runtime.h>

// Attention block: qkv proj -> RoPE -> causal GQA flash attention -> out proj.
// B=1, S=2048, H=2048, NH=32, KVH=8, D=64, G=4.
// R15/R18/R19: flash at ~45us. R21 (win 217->205): GBM 64 -> 2 blocks/CU for
//      the GEMMs (drain overlap), carved-smem exchange fix.
// R22: cast3 eliminated (5 kernels -> 4). gemm1 stages A=x and B=w_qkv
//      DIRECTLY from fp32 (2x float4 loads -> cvt -> ds_write_b128 to the
//      identical LDS offsets gload_lds used); gemm2 reg-stages B=w_o from
//      fp32, A=attn stays bf16 gload_lds. Numerics identical (same bf16
//      cast). Rationale: R21 raised staged bytes 1.5x and got FASTER ->
//      GEMMs are latency-bound, not LLC-BW-bound, so fp32 staging is cheap;
//      cast3's 132MB round-trip + a launch slot are pure savings.

typedef __bf16 bf16_t;
typedef __attribute__((ext_vector_type(8))) __bf16 bf16x8;
typedef __attribute__((ext_vector_type(4))) __bf16 bf16x4;
typedef __attribute__((ext_vector_type(4))) float f32x4;
typedef __attribute__((ext_vector_type(2))) unsigned int u32x2;
typedef __attribute__((ext_vector_type(4))) unsigned int u32x4;

#define S_LEN 2048
#define H_DIM 2048
#define NHEAD 32
#define KVH 8
#define HD 64
#define QKV_N 3072  // (NH + 2*KVH) * D

// split-K chunking: qt 0..7 direct; qt 8..63 split into ceil((qt+1)/8)
// chunks of 32-key tiles. Per kh: 8 direct + 280 split = 288 entries.
#define NE_PER_KH 288
#define NSPLIT_PER_KH 280
// partial entry: 4h*32r*64d bf16 (16384B) + 4h*32r lsum f32 (512B)
#define ENT_BYTES 16896

// ---------------- async 16B global -> LDS ----------------
__device__ __forceinline__ void async_copy16(bf16_t* lds_base, const bf16_t* g) {
  __builtin_amdgcn_global_load_lds(
      (const __attribute__((address_space(1))) unsigned int*)g,
      (__attribute__((address_space(3))) unsigned int*)lds_base, 16, 0, 0);
}

__device__ __forceinline__ bf16x8 cvt8(float4 a, float4 b) {
  bf16x8 v;
  v[0] = (bf16_t)a.x; v[1] = (bf16_t)a.y; v[2] = (bf16_t)a.z; v[3] = (bf16_t)a.w;
  v[4] = (bf16_t)b.x; v[5] = (bf16_t)b.y; v[6] = (bf16_t)b.z; v[7] = (bf16_t)b.w;
  return v;
}

// ---------------- GEMM: C[M,N] = A[M,K] * B[N,K]^T ----------------
// 64x128 tile, 512 threads = 8 waves. Wave wq owns a 32x64 C-subtile;
// gw=w>>2 processes K32-half gw of each BK=64 iter. Double-buffered staging,
// 1 raw barrier per iter. B always fp32-reg-staged (cvt in flight).
// AF32=1: A fp32-reg-staged too.  AF32=0: A bf16 via global_load_lds.
// EPI=0: C fp32 plain.  EPI=1: fused qkv epilogue (RoPE q/k, V transpose).
#define GBM 64
#define GBN 128

template <int EPI, int AF32>
__global__ __launch_bounds__(512, 4) void gemm_sk(const void* __restrict__ Av,
                                                  const float* __restrict__ Bf,
                                                  float* __restrict__ C,
                                                  bf16_t* __restrict__ qb,
                                                  bf16_t* __restrict__ ktp,
                                                  bf16_t* __restrict__ vt2,
                                                  int M, int N, int K) {
  // single carved LDS block: As[2] at 0 (16KB), Bs[2] at +16KB (32KB).
  __shared__ __align__(16) bf16_t smem[(2 * GBM + 2 * GBN) * 64];
  bf16_t (*As)[GBM * 64] = (bf16_t(*)[GBM * 64])smem;
  bf16_t (*Bs)[GBN * 64] = (bf16_t(*)[GBN * 64])(smem + 2 * GBM * 64);

  const int tid  = threadIdx.x;
  const int lane = tid & 63;
  const int w    = tid >> 6;          // 0..7
  const int wq   = w & 3;             // subtile id
  const int gw   = w >> 2;            // K32 group
  const int wm   = (wq >> 1) * 32;
  const int wn   = (wq & 1) * 64;
  const int c    = lane & 15;
  const int quad = lane >> 4;

  // XCD-aware block swizzle (T1): grids 768/512 are %8==0 -> bijective.
  const int nwg = (int)(gridDim.x * gridDim.y);
  const int bid = (int)blockIdx.y * (int)gridDim.x + (int)blockIdx.x;
  const int swz = (bid & 7) * (nwg >> 3) + (bid >> 3);
  const int m0  = (swz / (int)gridDim.x) * GBM;
  const int n0  = (swz % (int)gridDim.x) * GBN;

  f32x4 acc[2][4] = {};

  const float*  Af = (const float*)Av  + (AF32 ? (size_t)m0 * K : 0);
  const bf16_t* Ab = (const bf16_t*)Av + (AF32 ? 0 : (size_t)m0 * K);
  const float*  Bb = Bf + (size_t)n0 * K;

  // staging per BK=64 iter: A = 512 chunks (64 rows x 8), B = 1024 chunks
  // (128 rows x 8). chunk p: row=p>>3, kc=(p&7)^(row&7). Thread tid owns
  // A-chunk tid and B-chunks {tid, 512+tid}; LDS dest = chunk p at p*8.
  const int arow = tid >> 3;
  const int akc  = (tid & 7) ^ (arow & 7);
  const int asb  = (w * 64) * 8;   // wave-uniform base for gload_lds path
  int brow[2], bkc[2];
#pragma unroll
  for (int i = 0; i < 2; ++i) {
    int p = i * 512 + tid;
    brow[i] = p >> 3;
    bkc[i]  = (p & 7) ^ (brow[i] & 7);
  }

  // in-flight fp32 staging registers (named; no runtime indexing)
  float4 rA0, rA1, rB00, rB01, rB10, rB11;

  auto ldregs = [&](int k0) {
    if (AF32) {
      const float* pa = Af + (size_t)arow * K + k0 + akc * 8;
      rA0 = ((const float4*)pa)[0];
      rA1 = ((const float4*)pa)[1];
    }
    const float* pb0 = Bb + (size_t)brow[0] * K + k0 + bkc[0] * 8;
    rB00 = ((const float4*)pb0)[0];
    rB01 = ((const float4*)pb0)[1];
    const float* pb1 = Bb + (size_t)brow[1] * K + k0 + bkc[1] * 8;
    rB10 = ((const float4*)pb1)[0];
    rB11 = ((const float4*)pb1)[1];
  };

  auto wrlds = [&](int buf) {
    if (AF32) *(bf16x8*)&As[buf][(size_t)tid * 8] = cvt8(rA0, rA1);
    *(bf16x8*)&Bs[buf][(size_t)tid * 8]         = cvt8(rB00, rB01);
    *(bf16x8*)&Bs[buf][(size_t)(512 + tid) * 8] = cvt8(rB10, rB11);
  };

  auto stageA_lds = [&](int buf, int k0) {   // AF32==0 path (A already bf16)
    async_copy16(&As[buf][asb], Ab + (size_t)arow * K + k0 + akc * 8);
  };

  auto compute = [&](int buf) {
    bf16x8 af[2], bfr[4];
#pragma unroll
    for (int mt = 0; mt < 2; ++mt) {
      int row = wm + mt * 16 + c;
      af[mt] = *(const bf16x8*)&As[buf][(row * 8 + ((gw * 4 + quad) ^ (row & 7))) * 8];
    }
#pragma unroll
    for (int nt = 0; nt < 4; ++nt) {
      int rowb = wn + nt * 16 + c;
      bfr[nt] = *(const bf16x8*)&Bs[buf][(rowb * 8 + ((gw * 4 + quad) ^ (rowb & 7))) * 8];
    }
#pragma unroll
    for (int mt = 0; mt < 2; ++mt)
#pragma unroll
      for (int nt = 0; nt < 4; ++nt)
        acc[mt][nt] = __builtin_amdgcn_mfma_f32_16x16x32_bf16(af[mt], bfr[nt], acc[mt][nt], 0, 0, 0);
  };

  const int NI = K >> 6;   // BK=64 iterations
  ldregs(0);
  if (!AF32) stageA_lds(0, 0);
  int buf = 0;
  for (int it = 0; it < NI; ++it) {
    wrlds(buf);                                        // cvt consumes rX (implicit vmcnt)
    asm volatile("s_waitcnt lgkmcnt(0) vmcnt(0)" ::: "memory");  // ds_writes + A gload done
    __builtin_amdgcn_s_barrier();                      // buf fully staged; buf^1 free
    if (it + 1 < NI) {
      ldregs((it + 1) << 6);
      if (!AF32) stageA_lds(buf ^ 1, (it + 1) << 6);
    }
    compute(buf);
    buf ^= 1;
  }

  // combine wave-pair partials through LDS: 4 subtiles x 8KB = 32KB over the
  // explicitly carved smem (dead staging data) -- guaranteed in-bounds.
  __syncthreads();
  float* xch = (float*)smem;
  if (gw == 1) {
#pragma unroll
    for (int t8 = 0; t8 < 8; ++t8)
      *(f32x4*)&xch[wq * 2048 + (t8 * 64 + lane) * 4] = acc[t8 >> 2][t8 & 3];
  }
  __syncthreads();
  if (gw == 0) {
#pragma unroll
    for (int t8 = 0; t8 < 8; ++t8) {
      f32x4 o = *(const f32x4*)&xch[wq * 2048 + (t8 * 64 + lane) * 4];
      acc[t8 >> 2][t8 & 3] += o;
    }

    if (EPI == 0) {
#pragma unroll
      for (int mt = 0; mt < 2; ++mt)
#pragma unroll
        for (int nt = 0; nt < 4; ++nt)
#pragma unroll
          for (int reg = 0; reg < 4; ++reg) {
            int row = m0 + wm + mt * 16 + quad * 4 + reg;
            int col = n0 + wn + nt * 16 + c;
            C[(size_t)row * N + col] = acc[mt][nt][reg];
          }
    } else {
      // fused qkv epilogue: wave covers one head's 64 cols (GBN unchanged).
      const int colb = n0 + wn;
      if (colb < NHEAD * HD) {
        const int h = colb >> 6;
#pragma unroll
        for (int nt = 0; nt < 2; ++nt) {
          const int i = nt * 16 + c;
          const float invf = __expf(-(float)i * (9.210340371976184f / 32.0f));
#pragma unroll
          for (int mt = 0; mt < 2; ++mt)
#pragma unroll
            for (int reg = 0; reg < 4; ++reg) {
              const int s = m0 + wm + mt * 16 + quad * 4 + reg;
              float sn, cs;
              __sincosf((float)s * invf, &sn, &cs);
              const float x1 = acc[mt][nt][reg], x2 = acc[mt][nt + 2][reg];
              bf16_t* q = qb + (size_t)s * H_DIM + h * HD;
              q[i]      = (bf16_t)((x1 * cs - x2 * sn) * 0.125f);
              q[i + 32] = (bf16_t)((x2 * cs + x1 * sn) * 0.125f);
            }
        }
      } else if (colb < NHEAD * HD + KVH * HD) {
        const int kh = (colb - NHEAD * HD) >> 6;
#pragma unroll
        for (int nt = 0; nt < 2; ++nt) {
          const int i = nt * 16 + c;
          const float invf = __expf(-(float)i * (9.210340371976184f / 32.0f));
#pragma unroll
          for (int mt = 0; mt < 2; ++mt)
#pragma unroll
            for (int reg = 0; reg < 4; ++reg) {
              const int s = m0 + wm + mt * 16 + quad * 4 + reg;
              float sn, cs;
              __sincosf((float)s * invf, &sn, &cs);
              const float x1 = acc[mt][nt][reg], x2 = acc[mt][nt + 2][reg];
              bf16_t* kd = ktp + ((size_t)kh * S_LEN + s) * HD;
              kd[i]      = (bf16_t)(x1 * cs - x2 * sn);
              kd[i + 32] = (bf16_t)(x2 * cs + x1 * sn);
            }
        }
      } else {
        const int kh = (colb - NHEAD * HD - KVH * HD) >> 6;
#pragma unroll
        for (int nt = 0; nt < 4; ++nt) {
          const int d = nt * 16 + c;
#pragma unroll
          for (int mt = 0; mt < 2; ++mt) {
            const int sr = m0 + wm + mt * 16 + quad * 4;
            bf16x4 pv;
#pragma unroll
            for (int reg = 0; reg < 4; ++reg) pv[reg] = (bf16_t)acc[mt][nt][reg];
            *(bf16x4*)&vt2[((size_t)kh * HD + d) * S_LEN + sr] = pv;
          }
        }
      }
    }
  }
}

// ---------------- split-K MFMA flash (KVBLK=32, R18/R19 state) ----------------
__global__ __launch_bounds__(256, 4) void flash_split(const bf16_t* __restrict__ qb,
                                                      const bf16_t* __restrict__ kt,
                                                      const bf16_t* __restrict__ vt2,
                                                      float* __restrict__ pbuf,
                                                      bf16_t* __restrict__ attn) {
  __shared__ __align__(16) bf16_t Ks[2][32 * 64];
  __shared__ __align__(16) bf16_t Vs[2][64 * 32];

  const int tid  = threadIdx.x;
  const int lane = tid & 63;
  const int w    = tid >> 6;
  const int e    = (int)gridDim.x - 1 - (int)blockIdx.x;   // long chunks first
  const int kh   = e / NE_PER_KH;
  const int j    = e - kh * NE_PER_KH;

  int qt, chunk, nch;
  if (j < 8) {
    qt = j; chunk = 0; nch = 1;
  } else {
    int j2 = j - 8;
    qt = 8;
    for (;;) {
      nch = (qt + 8) >> 3;          // ceil((qt+1)/8)
      if (j2 < nch) { chunk = j2; break; }
      j2 -= nch; ++qt;
    }
  }
  const int T       = qt + 1;       // 32-key tiles
  const int t_begin = (chunk * T) / nch;
  const int t_end   = ((chunk + 1) * T) / nch;

  const int s0    = qt * 32;
  const int h     = kh * 4 + w;
  const int c     = lane & 15;
  const int quad  = lane >> 4;

  const int idx0 = (c + (quad & 1) * 32) * 4;
  const int idx1 = idx0 + 64;
  const bool hiY = quad >= 2;

  bf16x8 qf[2][2];
#pragma unroll
  for (int rf = 0; rf < 2; ++rf)
#pragma unroll
    for (int ks = 0; ks < 2; ++ks)
      qf[rf][ks] = *(const bf16x8*)(qb + (size_t)(s0 + rf * 16 + c) * H_DIM + h * HD + ks * 32 + quad * 8);

  f32x4 acc[2][4] = {};
  float lsum[2] = {0.f, 0.f};

  const bf16_t* kbase = kt + (size_t)kh * S_LEN * HD;
  const bf16_t* vbase = vt2 + (size_t)kh * HD * S_LEN;

  const int krow = tid >> 3;
  const int kkc  = (tid & 7) ^ (krow & 7);
  const int vrow = tid >> 2;
  const int vkc  = (tid & 3) ^ ((vrow + (vrow >> 2)) & 3);
  const int sbase = w * 64 * 8;

  auto stage = [&](int buf, int tile) {
    const int t0 = tile * 32;
    async_copy16(&Ks[buf][sbase], kbase + (size_t)(t0 + krow) * HD + kkc * 8);
    async_copy16(&Vs[buf][sbase], vbase + (size_t)vrow * S_LEN + t0 + vkc * 8);
  };

  stage(0, t_begin);
  int buf = 0;
  for (int tile = t_begin; tile < t_end; ++tile) {
    const int t0 = tile * 32;
    asm volatile("s_waitcnt vmcnt(0)" ::: "memory");
    __builtin_amdgcn_s_barrier();
    if (tile + 1 < t_end) stage(buf ^ 1, tile + 1);

    const bool masked = (tile == T - 1);

    unsigned pw[2][2][2];   // [rf][kt2][word]
#pragma unroll
    for (int kt2 = 0; kt2 < 2; ++kt2) {
      bf16x8 kf0 = *(const bf16x8*)&Ks[buf][((kt2 * 16 + c) * 8 + ((quad) ^ (c & 7))) * 8];
      bf16x8 kf1 = *(const bf16x8*)&Ks[buf][((kt2 * 16 + c) * 8 + ((4 + quad) ^ (c & 7))) * 8];
#pragma unroll
      for (int rf = 0; rf < 2; ++rf) {
        f32x4 st = {};
        __builtin_amdgcn_s_setprio(1);
        st = __builtin_amdgcn_mfma_f32_16x16x32_bf16(kf0, qf[rf][0], st, 0, 0, 0);
        st = __builtin_amdgcn_mfma_f32_16x16x32_bf16(kf1, qf[rf][1], st, 0, 0, 0);
        __builtin_amdgcn_s_setprio(0);
        const int row = s0 + rf * 16 + c;
        bf16x4 pk;
#pragma unroll
        for (int reg = 0; reg < 4; ++reg) {
          const int key = t0 + kt2 * 16 + quad * 4 + reg;
          float p = __builtin_amdgcn_exp2f(fmaf(st[reg], 1.44269504f, -11.54156036f));
          if (masked && key > row) p = 0.f;
          pk[reg] = (bf16_t)p;
          lsum[rf] += p;
        }
        u32x2 pv2 = __builtin_bit_cast(u32x2, pk);
        pw[rf][kt2][0] = pv2.x;
        pw[rf][kt2][1] = pv2.y;
      }
    }

    bf16x8 vf[4];
#pragma unroll
    for (int dt = 0; dt < 4; ++dt)
      vf[dt] = *(const bf16x8*)&Vs[buf][((dt * 16 + c) * 4 + (quad ^ ((c + (c >> 2)) & 3))) * 8];

#pragma unroll
    for (int rf = 0; rf < 2; ++rf) {
      int lo, hi;
      u32x4 fwv;
      lo = __builtin_amdgcn_ds_bpermute(idx0, (int)pw[rf][0][0]);
      hi = __builtin_amdgcn_ds_bpermute(idx0, (int)pw[rf][1][0]);
      fwv.x = hiY ? (unsigned)hi : (unsigned)lo;
      lo = __builtin_amdgcn_ds_bpermute(idx0, (int)pw[rf][0][1]);
      hi = __builtin_amdgcn_ds_bpermute(idx0, (int)pw[rf][1][1]);
      fwv.y = hiY ? (unsigned)hi : (unsigned)lo;
      lo = __builtin_amdgcn_ds_bpermute(idx1, (int)pw[rf][0][0]);
      hi = __builtin_amdgcn_ds_bpermute(idx1, (int)pw[rf][1][0]);
      fwv.z = hiY ? (unsigned)hi : (unsigned)lo;
      lo = __builtin_amdgcn_ds_bpermute(idx1, (int)pw[rf][0][1]);
      hi = __builtin_amdgcn_ds_bpermute(idx1, (int)pw[rf][1][1]);
      fwv.w = hiY ? (unsigned)hi : (unsigned)lo;
      bf16x8 pa = __builtin_bit_cast(bf16x8, fwv);
      __builtin_amdgcn_s_setprio(1);
#pragma unroll
      for (int dt = 0; dt < 4; ++dt)
        acc[rf][dt] = __builtin_amdgcn_mfma_f32_16x16x32_bf16(pa, vf[dt], acc[rf][dt], 0, 0, 0);
      __builtin_amdgcn_s_setprio(0);
    }
    buf ^= 1;
  }

#pragma unroll
  for (int rf = 0; rf < 2; ++rf) {
    lsum[rf] += __shfl_xor(lsum[rf], 16);
    lsum[rf] += __shfl_xor(lsum[rf], 32);
  }

  __syncthreads();   // all Ks readers done before reusing Ks as lbuf
  if (j < 8) {
    float* lbuf = (float*)&Ks[0][0] + w * 32;
#pragma unroll
    for (int rf = 0; rf < 2; ++rf) lbuf[rf * 16 + c] = lsum[rf];
    asm volatile("s_waitcnt lgkmcnt(0)" ::: "memory");
#pragma unroll
    for (int rf = 0; rf < 2; ++rf)
#pragma unroll
      for (int reg = 0; reg < 4; ++reg) {
        const float inv = 1.0f / lbuf[rf * 16 + quad * 4 + reg];
        const int row = s0 + rf * 16 + quad * 4 + reg;
#pragma unroll
        for (int dt = 0; dt < 4; ++dt)
          attn[(size_t)row * H_DIM + h * HD + dt * 16 + c] = (bf16_t)(acc[rf][dt][reg] * inv);
      }
  } else {
    const int slot = kh * NSPLIT_PER_KH + (j - 8);
    char* ent = (char*)pbuf + (size_t)slot * ENT_BYTES;
    bf16_t* eo = (bf16_t*)ent;
    float*  el = (float*)(ent + 16384);
#pragma unroll
    for (int rf = 0; rf < 2; ++rf) {
#pragma unroll
      for (int dt = 0; dt < 4; ++dt)
#pragma unroll
        for (int reg = 0; reg < 4; ++reg)
          eo[w * 2048 + (rf * 16 + quad * 4 + reg) * 64 + dt * 16 + c] = (bf16_t)acc[rf][dt][reg];
      el[w * 32 + rf * 16 + c] = lsum[rf];
    }
  }
}

// ---------------- reduce: sum bf16 partial chunks, normalize, write attn ----
__global__ __launch_bounds__(256) void flash_reduce(const float* __restrict__ pbuf,
                                                    bf16_t* __restrict__ attn) {
  const int kh = blockIdx.x / 56;
  const int qt = 8 + (blockIdx.x % 56);

  int base = 0;
  for (int q = 8; q < qt; ++q) base += (q + 8) >> 3;
  const int nch = (qt + 8) >> 3;
  base += kh * NSPLIT_PER_KH;

  const int t   = threadIdx.x;
  const int h2  = t >> 6;
  const int row = (t >> 1) & 31;
  const int dh  = t & 1;

  f32x4 o[8] = {};
  float l = 0.f;
  for (int ci = 0; ci < nch; ++ci) {
    const char* ent = (const char*)pbuf + (size_t)(base + ci) * ENT_BYTES;
    const bf16_t* p = (const bf16_t*)ent + h2 * 2048 + row * 64 + dh * 32;
#pragma unroll
    for (int jj = 0; jj < 8; ++jj) {
      bf16x4 v = ((const bf16x4*)p)[jj];
      o[jj][0] += (float)v[0]; o[jj][1] += (float)v[1];
      o[jj][2] += (float)v[2]; o[jj][3] += (float)v[3];
    }
    l += ((const float*)(ent + 16384))[h2 * 32 + row];
  }
  const float inv = 1.0f / l;
  bf16_t* dst = attn + (size_t)(qt * 32 + row) * H_DIM + (kh * 4 + h2) * 64 + dh * 32;
#pragma unroll
  for (int jj = 0; jj < 8; ++jj) {
    bf16x4 ov;
    ov[0] = (bf16_t)(o[jj][0] * inv); ov[1] = (bf16_t)(o[jj][1] * inv);
    ov[2] = (bf16_t)(o[jj][2] * inv); ov[3] = (bf16_t)(o[jj][3] * inv);
    *(bf16x4*)(dst + jj * 4) = ov;
  }
}

// ---------------- launch ----------------
extern "C" void kernel_launch(void* const* d_in, const int* in_sizes, int n_in,
                              void* d_out, int out_size, void* d_ws, size_t ws_size,
                              hipStream_t stream) {
  const float* x     = (const float*)d_in[0];
  const float* w_qkv = (const float*)d_in[1];
  const float* w_o   = (const float*)d_in[2];
  float* out = (float*)d_out;

  char* ws = (char*)d_ws;
  const size_t OVERLAY = (size_t)1280 * 8320 * 4;  // 42.6 MB (pbuf needs 37.8MB)
  float*  pbuf    = (float*)ws;
  size_t off = OVERLAY;
  bf16_t* q_bf    = (bf16_t*)(ws + off); off += (size_t)S_LEN * H_DIM * 2;
  bf16_t* k_t     = (bf16_t*)(ws + off); off += (size_t)KVH * S_LEN * HD * 2;
  bf16_t* v_t2    = (bf16_t*)(ws + off); off += (size_t)KVH * S_LEN * HD * 2;
  bf16_t* attn    = (bf16_t*)(ws + off); off += (size_t)S_LEN * H_DIM * 2;

  gemm_sk<1, 1><<<dim3(QKV_N / GBN, S_LEN / GBM), 512, 0, stream>>>(
      x, w_qkv, nullptr, q_bf, k_t, v_t2, S_LEN, QKV_N, H_DIM);

  flash_split<<<8 * NE_PER_KH, 256, 0, stream>>>(q_bf, k_t, v_t2, pbuf, attn);
  flash_reduce<<<8 * 56, 256, 0, stream>>>(pbuf, attn);

  gemm_sk<0, 0><<<dim3(H_DIM / GBN, S_LEN / GBM), 512, 0, stream>>>(
      attn, w_o, out, nullptr, nullptr, nullptr, S_LEN, H_DIM, H_DIM);
}